// Round 1
// baseline (6205.922 us; speedup 1.0000x reference)
//
#include <hip/hip_runtime.h>
#include <hip/hip_bf16.h>
#include <stdint.h>

#define M_TOK 32768
#define TOPK  2
#define HID   2048
#define FFN   4096
#define NEXP  8
#define MK    (M_TOK * TOPK)   // 65536 rows
#define BM    128
#define BN    128
#define BK    64
#define MAX_TILES 520          // 65536/128 + 8 experts worst-case remainders

typedef __bf16 bf16x8 __attribute__((ext_vector_type(8)));
typedef float  f32x4  __attribute__((ext_vector_type(4)));

__device__ __forceinline__ unsigned short f2bf(float f) {
    unsigned int u = __float_as_uint(f);
    u = (u + 0x7fffu + ((u >> 16) & 1u)) >> 16;   // RNE
    return (unsigned short)u;
}

// async global->LDS, 16B per lane. LDS dest must be wave-uniform base + lane*16.
__device__ __forceinline__ void async16(const void* g, void* l) {
    __builtin_amdgcn_global_load_lds((__attribute__((address_space(1))) void*)(g),
                                     (__attribute__((address_space(3))) void*)(l),
                                     16, 0, 0);
}

// ---------------- routing ----------------

__global__ void k_zero_meta(int* meta) {
    if (threadIdx.x < 32) meta[threadIdx.x] = 0;
}

__global__ void k_hist(const int* __restrict__ top, int* __restrict__ counts) {
    __shared__ int lc[NEXP];
    if (threadIdx.x < NEXP) lc[threadIdx.x] = 0;
    __syncthreads();
    int i = blockIdx.x * blockDim.x + threadIdx.x;
    int stride = gridDim.x * blockDim.x;
    for (; i < MK; i += stride) atomicAdd(&lc[top[i]], 1);
    __syncthreads();
    if (threadIdx.x < NEXP) atomicAdd(&counts[threadIdx.x], lc[threadIdx.x]);
}

__global__ void k_tiles(const int* __restrict__ counts, int* __restrict__ cursors,
                        int* __restrict__ num_tiles, int* __restrict__ tile_e,
                        int* __restrict__ tile_row0, int* __restrict__ tile_rows) {
    if (threadIdx.x == 0 && blockIdx.x == 0) {
        int off = 0, nt = 0;
        for (int e = 0; e < NEXP; ++e) {
            int c = counts[e];
            cursors[e] = off;
            for (int t0 = 0; t0 < c; t0 += BM) {
                tile_e[nt] = e;
                tile_row0[nt] = off + t0;
                tile_rows[nt] = (c - t0) < BM ? (c - t0) : BM;
                ++nt;
            }
            off += c;
        }
        *num_tiles = nt;
    }
}

__global__ void k_scatter(const int* __restrict__ top, int* __restrict__ cursors,
                          int* __restrict__ sorted_ids) {
    int i = blockIdx.x * blockDim.x + threadIdx.x;
    int stride = gridDim.x * blockDim.x;
    for (; i < MK; i += stride) {
        int e = top[i];
        int pos = atomicAdd(&cursors[e], 1);
        sorted_ids[pos] = i;
    }
}

// ---------------- conversions ----------------

__global__ void k_cvt_x(const float* __restrict__ x, unsigned short* __restrict__ xb) {
    const int n4 = (M_TOK * HID) / 4;
    int i = blockIdx.x * blockDim.x + threadIdx.x;
    int stride = gridDim.x * blockDim.x;
    for (; i < n4; i += stride) {
        float4 v = ((const float4*)x)[i];
        ushort4 o;
        o.x = f2bf(v.x); o.y = f2bf(v.y); o.z = f2bf(v.z); o.w = f2bf(v.w);
        ((ushort4*)xb)[i] = o;
    }
}

// in: [E][R][C] fp32 row-major -> out: [E][C][R] bf16
__global__ void k_transpose_cvt(const float* __restrict__ in, unsigned short* __restrict__ out,
                                int R, int C) {
    __shared__ unsigned short tile[32][33];
    const int e = blockIdx.z;
    const float* pin = in + (size_t)e * R * C;
    unsigned short* pout = out + (size_t)e * R * C;
    const int c0 = blockIdx.x * 32, r0 = blockIdx.y * 32;
    const int tx = threadIdx.x, ty = threadIdx.y;   // blockDim = (32, 8)
#pragma unroll
    for (int j = 0; j < 32; j += 8)
        tile[ty + j][tx] = f2bf(pin[(size_t)(r0 + ty + j) * C + (c0 + tx)]);
    __syncthreads();
#pragma unroll
    for (int j = 0; j < 32; j += 8)
        pout[(size_t)(c0 + ty + j) * R + (r0 + tx)] = tile[tx][ty + j];
}

// ---------------- pass 1: h = silu(x@w1) * (x@w3), grouped ----------------

__launch_bounds__(256, 2)
__global__ void k_gemm1(const unsigned short* __restrict__ xb,
                        const unsigned short* __restrict__ w1t,
                        const unsigned short* __restrict__ w3t,
                        const int* __restrict__ sorted_ids,
                        const int* __restrict__ num_tiles,
                        const int* __restrict__ tile_e,
                        const int* __restrict__ tile_row0,
                        const int* __restrict__ tile_rows,
                        unsigned short* __restrict__ h) {
    if ((int)blockIdx.x >= *num_tiles) return;
    __shared__ unsigned short sA[BM * BK];    // [m][k]
    __shared__ unsigned short sB1[BN * BK];   // [n][k]
    __shared__ unsigned short sB3[BN * BK];
    __shared__ int s_tok[BM];

    const int e    = tile_e[blockIdx.x];
    const int row0 = tile_row0[blockIdx.x];
    const int nrow = tile_rows[blockIdx.x];
    const int n0   = blockIdx.y * BN;

    const int t = threadIdx.x;
    const int lane = t & 63, wave = t >> 6;
    const int wm = wave & 1, wn = wave >> 1;

    if (t < BM) {
        int r = t < nrow ? t : (nrow - 1);
        s_tok[t] = sorted_ids[row0 + r] >> 1;   // TOPK==2
    }
    __syncthreads();

    const int sub = lane >> 3;   // row within 8-row group
    const int kb  = lane & 7;    // 16B chunk within a 128B row segment
    const unsigned short* gA[4];
    const unsigned short* gB1[4];
    const unsigned short* gB3[4];
#pragma unroll
    for (int s = 0; s < 4; ++s) {
        int r = (wave * 4 + s) * 8 + sub;             // 0..127
        gA[s]  = xb  + (size_t)s_tok[r] * HID + kb * 8;
        int n = n0 + (wave * 4 + s) * 8 + sub;
        gB1[s] = w1t + ((size_t)e * FFN + n) * HID + kb * 8;
        gB3[s] = w3t + ((size_t)e * FFN + n) * HID + kb * 8;
    }

    f32x4 acc1[4][4], acc3[4][4];
#pragma unroll
    for (int i = 0; i < 4; ++i)
#pragma unroll
        for (int j = 0; j < 4; ++j) {
            acc1[i][j] = (f32x4){0.f, 0.f, 0.f, 0.f};
            acc3[i][j] = (f32x4){0.f, 0.f, 0.f, 0.f};
        }

    for (int it = 0; it < HID / BK; ++it) {
        __syncthreads();
        const int ldsoff = wave * 4 * 512 + lane * 8;
#pragma unroll
        for (int s = 0; s < 4; ++s) {
            async16(gA[s],  sA  + ldsoff + s * 512);  gA[s]  += BK;
            async16(gB1[s], sB1 + ldsoff + s * 512);  gB1[s] += BK;
            async16(gB3[s], sB3 + ldsoff + s * 512);  gB3[s] += BK;
        }
        asm volatile("s_waitcnt vmcnt(0)" ::: "memory");
        __syncthreads();
#pragma unroll
        for (int kk = 0; kk < 2; ++kk) {
            bf16x8 a[4], b1[4], b3[4];
#pragma unroll
            for (int i = 0; i < 4; ++i) {
                int mrow = wm * 64 + i * 16 + (lane & 15);
                a[i]  = *(const bf16x8*)(sA  + mrow * BK + kk * 32 + (lane >> 4) * 8);
                int ncol = wn * 64 + i * 16 + (lane & 15);
                b1[i] = *(const bf16x8*)(sB1 + ncol * BK + kk * 32 + (lane >> 4) * 8);
                b3[i] = *(const bf16x8*)(sB3 + ncol * BK + kk * 32 + (lane >> 4) * 8);
            }
#pragma unroll
            for (int i = 0; i < 4; ++i)
#pragma unroll
                for (int j = 0; j < 4; ++j) {
                    acc1[i][j] = __builtin_amdgcn_mfma_f32_16x16x32_bf16(a[i], b1[j], acc1[i][j], 0, 0, 0);
                    acc3[i][j] = __builtin_amdgcn_mfma_f32_16x16x32_bf16(a[i], b3[j], acc3[i][j], 0, 0, 0);
                }
        }
    }

    const int q = lane >> 4, cl = lane & 15;
#pragma unroll
    for (int i = 0; i < 4; ++i)
#pragma unroll
        for (int j = 0; j < 4; ++j)
#pragma unroll
            for (int r = 0; r < 4; ++r) {
                int row = wm * 64 + i * 16 + q * 4 + r;
                if (row < nrow) {
                    int col = n0 + wn * 64 + j * 16 + cl;
                    float v1 = acc1[i][j][r];
                    float v3 = acc3[i][j][r];
                    float sig = 1.f / (1.f + __expf(-v1));
                    h[(size_t)(row0 + row) * FFN + col] = f2bf(v1 * sig * v3);
                }
            }
}

// ---------------- pass 2: out = h @ w2, scatter to token order ----------------

__launch_bounds__(256, 2)
__global__ void k_gemm2(const unsigned short* __restrict__ h,
                        const unsigned short* __restrict__ w2t,
                        const int* __restrict__ sorted_ids,
                        const int* __restrict__ num_tiles,
                        const int* __restrict__ tile_e,
                        const int* __restrict__ tile_row0,
                        const int* __restrict__ tile_rows,
                        float* __restrict__ out) {
    if ((int)blockIdx.x >= *num_tiles) return;
    __shared__ unsigned short sA[BM * BK];
    __shared__ unsigned short sB[BN * BK];
    __shared__ int s_id[BM];

    const int e    = tile_e[blockIdx.x];
    const int row0 = tile_row0[blockIdx.x];
    const int nrow = tile_rows[blockIdx.x];
    const int n0   = blockIdx.y * BN;

    const int t = threadIdx.x;
    const int lane = t & 63, wave = t >> 6;
    const int wm = wave & 1, wn = wave >> 1;

    if (t < BM) {
        int r = t < nrow ? t : (nrow - 1);
        s_id[t] = sorted_ids[row0 + r];
    }
    __syncthreads();

    const int sub = lane >> 3, kb = lane & 7;
    const unsigned short* gA[4];
    const unsigned short* gB[4];
#pragma unroll
    for (int s = 0; s < 4; ++s) {
        int r = (wave * 4 + s) * 8 + sub;
        gA[s] = h + (size_t)(row0 + r) * FFN + kb * 8;          // h padded by BM rows
        int n = n0 + (wave * 4 + s) * 8 + sub;
        gB[s] = w2t + ((size_t)e * HID + n) * FFN + kb * 8;
    }

    f32x4 acc[4][4];
#pragma unroll
    for (int i = 0; i < 4; ++i)
#pragma unroll
        for (int j = 0; j < 4; ++j) acc[i][j] = (f32x4){0.f, 0.f, 0.f, 0.f};

    for (int it = 0; it < FFN / BK; ++it) {
        __syncthreads();
        const int ldsoff = wave * 4 * 512 + lane * 8;
#pragma unroll
        for (int s = 0; s < 4; ++s) {
            async16(gA[s], sA + ldsoff + s * 512);  gA[s] += BK;
            async16(gB[s], sB + ldsoff + s * 512);  gB[s] += BK;
        }
        asm volatile("s_waitcnt vmcnt(0)" ::: "memory");
        __syncthreads();
#pragma unroll
        for (int kk = 0; kk < 2; ++kk) {
            bf16x8 a[4], b[4];
#pragma unroll
            for (int i = 0; i < 4; ++i) {
                int mrow = wm * 64 + i * 16 + (lane & 15);
                a[i] = *(const bf16x8*)(sA + mrow * BK + kk * 32 + (lane >> 4) * 8);
                int ncol = wn * 64 + i * 16 + (lane & 15);
                b[i] = *(const bf16x8*)(sB + ncol * BK + kk * 32 + (lane >> 4) * 8);
            }
#pragma unroll
            for (int i = 0; i < 4; ++i)
#pragma unroll
                for (int j = 0; j < 4; ++j)
                    acc[i][j] = __builtin_amdgcn_mfma_f32_16x16x32_bf16(a[i], b[j], acc[i][j], 0, 0, 0);
        }
    }

    const int q = lane >> 4, cl = lane & 15;
#pragma unroll
    for (int i = 0; i < 4; ++i)
#pragma unroll
        for (int j = 0; j < 4; ++j)
#pragma unroll
            for (int r = 0; r < 4; ++r) {
                int row = wm * 64 + i * 16 + q * 4 + r;
                if (row < nrow) {
                    int id = s_id[row];
                    int col = n0 + wn * 64 + j * 16 + cl;
                    out[(size_t)id * HID + col] = acc[i][j][r];
                }
            }
}

// ---------------- launch ----------------

extern "C" void kernel_launch(void* const* d_in, const int* in_sizes, int n_in,
                              void* d_out, int out_size, void* d_ws, size_t ws_size,
                              hipStream_t stream) {
    const float* x   = (const float*)d_in[0];
    const int*   top = (const int*)d_in[1];
    const float* w1  = (const float*)d_in[2];
    const float* w2  = (const float*)d_in[3];
    const float* w3  = (const float*)d_in[4];
    float* out = (float*)d_out;

    char* p = (char*)d_ws;
    unsigned short* xb  = (unsigned short*)p;  p += (size_t)M_TOK * HID * 2;
    unsigned short* w1t = (unsigned short*)p;  p += (size_t)NEXP * HID * FFN * 2;
    unsigned short* w3t = (unsigned short*)p;  p += (size_t)NEXP * HID * FFN * 2;
    unsigned short* w2t = (unsigned short*)p;  p += (size_t)NEXP * HID * FFN * 2;
    unsigned short* hbuf = (unsigned short*)p; p += (size_t)(MK + BM) * FFN * 2;
    int* meta       = (int*)p;                 p += 32 * sizeof(int);
    int* tile_e     = (int*)p;                 p += MAX_TILES * sizeof(int);
    int* tile_row0  = (int*)p;                 p += MAX_TILES * sizeof(int);
    int* tile_rows  = (int*)p;                 p += MAX_TILES * sizeof(int);
    int* sorted_ids = (int*)p;                 p += (size_t)MK * sizeof(int);
    int* counts   = meta;        // [0..7]
    int* cursors  = meta + 8;    // [8..15]
    int* num_tiles = meta + 16;

    // routing
    k_zero_meta<<<1, 64, 0, stream>>>(meta);
    k_hist<<<64, 256, 0, stream>>>(top, counts);
    k_tiles<<<1, 1, 0, stream>>>(counts, cursors, num_tiles, tile_e, tile_row0, tile_rows);
    k_scatter<<<64, 256, 0, stream>>>(top, cursors, sorted_ids);

    // dtype conversion / weight transposes
    k_cvt_x<<<8192, 256, 0, stream>>>(x, xb);
    k_transpose_cvt<<<dim3(FFN / 32, HID / 32, NEXP), dim3(32, 8), 0, stream>>>(w1, w1t, HID, FFN);
    k_transpose_cvt<<<dim3(FFN / 32, HID / 32, NEXP), dim3(32, 8), 0, stream>>>(w3, w3t, HID, FFN);
    k_transpose_cvt<<<dim3(HID / 32, FFN / 32, NEXP), dim3(32, 8), 0, stream>>>(w2, w2t, FFN, HID);

    // grouped GEMMs
    k_gemm1<<<dim3(MAX_TILES, FFN / BN), 256, 0, stream>>>(
        xb, w1t, w3t, sorted_ids, num_tiles, tile_e, tile_row0, tile_rows, hbuf);
    k_gemm2<<<dim3(MAX_TILES, HID / BN), 256, 0, stream>>>(
        hbuf, w2t, sorted_ids, num_tiles, tile_e, tile_row0, tile_rows, out);
}